// Round 10
// baseline (339.658 us; speedup 1.0000x reference)
//
#include <hip/hip_runtime.h>
#include <hip/hip_bf16.h>
#include <stdint.h>

// Problem constants (reference: LoRA adapter forward)
#define TOKENS   8192
#define DIM      4096
#define DIM_OUT  4096
#define LORA_R   16
#define LORA_SCALE 2.0f

typedef __bf16 bf16_t;
typedef __attribute__((ext_vector_type(8))) __bf16 bfrag;   // 8 bf16 = 4 VGPR (MFMA A/B frag)
typedef __attribute__((ext_vector_type(4))) float f32x4;    // MFMA C/D frag

// ---------------------------------------------------------------------------
// async global->LDS, 16B per lane (global_load_lds_dwordx4)
// ---------------------------------------------------------------------------
__device__ __forceinline__ void gload_lds16(const bf16_t* gsrc, bf16_t* ldst) {
    __builtin_amdgcn_global_load_lds(
        (const __attribute__((address_space(1))) uint32_t*)(const void*)gsrc,
        (__attribute__((address_space(3))) uint32_t*)(void*)ldst,
        16, 0, 0);
}

// ---------------------------------------------------------------------------
// Kernel 1: fused prep (R4/R6-validated form).
// Blocks [0,2048): cast x fp32->bf16.  Blocks [2048,4096): Weff.
// ---------------------------------------------------------------------------
#define CAST_BLOCKS 2048
__global__ void prep_kernel(const float* __restrict__ x, bf16_t* __restrict__ xb,
                            const float* __restrict__ W, const float* __restrict__ A,
                            const float* __restrict__ B, bf16_t* __restrict__ Wt) {
    if (blockIdx.x < CAST_BLOCKS) {
        const int total = TOKENS * DIM / 8;
        for (int i = blockIdx.x * blockDim.x + threadIdx.x; i < total;
             i += CAST_BLOCKS * 256) {
            const float4* p = reinterpret_cast<const float4*>(x + (size_t)i * 8);
            float4 v0 = p[0], v1 = p[1];
            union { bf16_t o[8]; uint4 u; } pk;
            pk.o[0] = (bf16_t)v0.x; pk.o[1] = (bf16_t)v0.y;
            pk.o[2] = (bf16_t)v0.z; pk.o[3] = (bf16_t)v0.w;
            pk.o[4] = (bf16_t)v1.x; pk.o[5] = (bf16_t)v1.y;
            pk.o[6] = (bf16_t)v1.z; pk.o[7] = (bf16_t)v1.w;
            *reinterpret_cast<uint4*>(xb + (size_t)i * 8) = pk.u;
        }
    } else {
        int idx = (blockIdx.x - CAST_BLOCKS) * blockDim.x + threadIdx.x;
        int k0 = (idx & 511) << 3;          // 512 k-groups of 8
        int n0 = (idx >> 9) << 2;           // 1024 n-groups of 4

        float bn[4][16];
#pragma unroll
        for (int r = 0; r < 16; ++r) {
            float4 bv = *reinterpret_cast<const float4*>(B + (size_t)r * DIM_OUT + n0);
            bn[0][r] = bv.x; bn[1][r] = bv.y; bn[2][r] = bv.z; bn[3][r] = bv.w;
        }
        float ab[4][8];
#pragma unroll
        for (int j = 0; j < 8; ++j) {
            const float4* ap = reinterpret_cast<const float4*>(A + (size_t)(k0 + j) * LORA_R);
            float4 a0 = ap[0], a1 = ap[1], a2 = ap[2], a3 = ap[3];
            float av[16] = {a0.x,a0.y,a0.z,a0.w,a1.x,a1.y,a1.z,a1.w,
                            a2.x,a2.y,a2.z,a2.w,a3.x,a3.y,a3.z,a3.w};
#pragma unroll
            for (int n = 0; n < 4; ++n) {
                float s = 0.f;
#pragma unroll
                for (int r = 0; r < 16; ++r) s += av[r] * bn[n][r];
                ab[n][j] = s;
            }
        }
#pragma unroll
        for (int n = 0; n < 4; ++n) {
            const float4* wp = reinterpret_cast<const float4*>(W + (size_t)(n0 + n) * DIM + k0);
            float4 w0 = wp[0], w1 = wp[1];
            float wv[8] = {w0.x,w0.y,w0.z,w0.w,w1.x,w1.y,w1.z,w1.w};
            union { bf16_t o[8]; uint4 u; } pk;
#pragma unroll
            for (int j = 0; j < 8; ++j) pk.o[j] = (bf16_t)(wv[j] + LORA_SCALE * ab[n][j]);
            *reinterpret_cast<uint4*>(Wt + (size_t)(n0 + n) * DIM + k0) = pk.u;
        }
    }
}

// ---------------------------------------------------------------------------
// Kernel 2: 256x256 GEMM, BK=32, 4 LDS buffers, depth-2 prefetch:
// free-run tile body (no intra-tile barriers) + counted vmcnt(4) boundary.
// C[m][n] = sum_k Xb[m][k]*Wt[n][k] + bias[n]
// 512 thr = 8 waves (2M x 4N); per-wave 128x64 out = acc[8][4] 16x16 frags.
// LDS: 4 buf x (A 256x32 + B 256x32) bf16 = 128 KiB.
//
// Per K-tile t (read buf t&3):
//   stage tile t+2 -> buf (t+2)&3   (4 gload_lds, issued first)
//   12 ds_read_b128 (B then A) + 32 MFMA -- NO intra-tile barriers: reads
//   touch buf[t], writes buf[t+2] (disjoint), compiler interleaves with
//   fine lgkm counts, waves drift -> LDS pipe overlaps matrix pipe.
//   vmcnt(4) (retires tile t+1's stages, keeps t+2's 4 in flight -- never
//   drains to 0) ; s_barrier.
// Hazards (barrier-counted, no timing assumptions): buf[t] written at
// tiles t-2..t-1 boundary (vmcnt(4)@t-1-end + barrier), read in tile t,
// overwritten by stages issued at tile t+2 -- 2 barriers after the last
// reader retired (reads consumed by MFMAs within tile t).
//
// BK=32 swizzle (derived, <=2-way): col-slot cs' = cs ^ ((row>>1)&3);
// staging uses linear LDS dest + inverse-swizzled global col
// koff = ((tid&3) ^ ((tid>>3)&3)) * 8  (row+128 preserves the key: 64%4==0);
// ds_read col = ((lane>>4) ^ (((lane&15)>>1)&3)) * 8.
// ---------------------------------------------------------------------------
#define BM 256
#define BN 256
#define BK 32
#define MB_BLKS (TOKENS / BM)    // 32
#define NB_BLKS (DIM_OUT / BN)   // 16
#define NT      (DIM / BK)       // 128 K-tiles

#define SB0() __builtin_amdgcn_sched_barrier(0)
#define VMWAIT_(n) asm volatile("s_waitcnt vmcnt(" #n ")" ::: "memory")
#define VMWAIT(n) VMWAIT_(n)

__global__ __launch_bounds__(512, 2) void gemm_kernel(
    const bf16_t* __restrict__ Xb, const bf16_t* __restrict__ Wt,
    const float* __restrict__ bias, float* __restrict__ C)
{
    __shared__ __align__(16) bf16_t sA[4][BM][BK];   // 64 KiB
    __shared__ __align__(16) bf16_t sB[4][BN][BK];   // 64 KiB

    const int nwg = MB_BLKS * NB_BLKS;               // 512, %8==0 -> bijective
    int bid = blockIdx.x;
    int swz = (bid & 7) * (nwg >> 3) + (bid >> 3);   // XCD-aware remap
    int bm = swz / NB_BLKS;
    int bn = swz % NB_BLKS;

    const int tid  = threadIdx.x;
    const int lane = tid & 63;
    const int wid  = tid >> 6;       // 0..7
    const int wr   = wid >> 2;       // 0..1  (M half: 128 rows)
    const int wc   = wid & 3;        // 0..3  (N quarter: 64 cols)

    // ---- staging constants (linear LDS dest, pre-swizzled global src) ----
    const int srow = tid >> 2;                       // 0..127
    const int slin = (tid & 3) * 8;                  // linear col slot (elems)
    const int koff = (((tid & 3) ^ ((tid >> 3) & 3)) * 8); // swizzled src col
    const bf16_t* Ag = Xb + (size_t)(bm * BM + srow) * DIM + koff;
    const bf16_t* Bg = Wt + (size_t)(bn * BN + srow) * DIM + koff;

#define STAGE_A(sb, kt) do { \
    const bf16_t* s_ = Ag + (size_t)(kt) * BK; \
    gload_lds16(s_,                     &sA[sb][srow][slin]); \
    gload_lds16(s_ + (size_t)128 * DIM, &sA[sb][128 + srow][slin]); \
} while (0)

#define STAGE_B(sb, kt) do { \
    const bf16_t* s_ = Bg + (size_t)(kt) * BK; \
    gload_lds16(s_,                     &sB[sb][srow][slin]); \
    gload_lds16(s_ + (size_t)128 * DIM, &sB[sb][128 + srow][slin]); \
} while (0)

    // ---- fragment-read constants (swizzled) ----
    const int r15  = lane & 15;
    const int cK   = (((lane >> 4) ^ ((r15 >> 1) & 3))) * 8;  // swizzled col
    const int arow0 = wr * 128 + r15;                // + m*16
    const int brow0 = wc * 64  + r15;                // + n*16

    f32x4 acc[8][4] = {};
    bfrag a[8], b[4];

// One K-tile: read buf rb; optionally stage tile ktn -> buf sb.
// B reads first (first MFMAs depend on b0-3 + a0 only), then A.
#define TILE(rb, sb, ktn, S, VM) do { \
    if (S) { STAGE_A(sb, ktn); STAGE_B(sb, ktn); } \
    _Pragma("unroll") \
    for (int n_ = 0; n_ < 4; ++n_) \
        b[n_] = *reinterpret_cast<const bfrag*>(&sB[rb][brow0 + n_ * 16][cK]); \
    _Pragma("unroll") \
    for (int m_ = 0; m_ < 8; ++m_) \
        a[m_] = *reinterpret_cast<const bfrag*>(&sA[rb][arow0 + m_ * 16][cK]); \
    __builtin_amdgcn_s_setprio(1); \
    _Pragma("unroll") \
    for (int m_ = 0; m_ < 8; ++m_) \
    _Pragma("unroll") \
    for (int n_ = 0; n_ < 4; ++n_) \
        acc[m_][n_] = __builtin_amdgcn_mfma_f32_16x16x32_bf16( \
            a[m_], b[n_], acc[m_][n_], 0, 0, 0); \
    __builtin_amdgcn_s_setprio(0); \
    SB0(); VMWAIT(VM); __builtin_amdgcn_s_barrier(); SB0(); \
} while (0)

    // ---- prologue: tiles 0,1,2 -> bufs 0,1,2 (12 gloads) ----
    STAGE_A(0, 0); STAGE_B(0, 0);
    STAGE_A(1, 1); STAGE_B(1, 1);
    STAGE_A(2, 2); STAGE_B(2, 2);
    VMWAIT(8);          // tile 0 landed; tiles 1,2 (8 loads) stay in flight
    __builtin_amdgcn_s_barrier(); SB0();

    // ---- main loop: tiles 0..123 (31 iterations x 4), staging t+2 ----
    for (int it = 0; it < NT / 4 - 1; ++it) {
        int t = 4 * it;
        TILE(0, 2, t + 2, true, 4);
        TILE(1, 3, t + 3, true, 4);
        TILE(2, 0, t + 4, true, 4);
        TILE(3, 1, t + 5, true, 4);
    }
    // ---- peeled tiles 124..127 ----
    TILE(0, 2, 126, true,  4);
    TILE(1, 3, 127, true,  4);
    TILE(2, 0, 0,   false, 0);   // drain: tile 127's loads must land
    TILE(3, 1, 0,   false, 0);

    // ---- epilogue: D layout row=(lane>>4)*4+j, col=lane&15 ----
    int row0 = bm * BM + wr * 128 + (lane >> 4) * 4;
    int col0 = bn * BN + wc * 64 + r15;
#pragma unroll
    for (int n = 0; n < 4; ++n) {
        int c = col0 + n * 16;
        float bv = bias[c];
#pragma unroll
        for (int m = 0; m < 8; ++m) {
            int r = row0 + m * 16;
#pragma unroll
            for (int j = 0; j < 4; ++j)
                C[(size_t)(r + j) * DIM_OUT + c] = acc[m][n][j] + bv;
        }
    }
}

// ---------------------------------------------------------------------------
extern "C" void kernel_launch(void* const* d_in, const int* in_sizes, int n_in,
                              void* d_out, int out_size, void* d_ws, size_t ws_size,
                              hipStream_t stream) {
    const float* x = (const float*)d_in[0];
    const float* A = (const float*)d_in[1];
    const float* B = (const float*)d_in[2];
    const float* W = (const float*)d_in[3];
    const float* b = (const float*)d_in[4];
    float* out = (float*)d_out;

    // workspace: xb (8192*4096 bf16 = 64MB) | Wt (4096*4096 bf16 = 32MB)
    bf16_t* xb = (bf16_t*)d_ws;
    bf16_t* Wt = (bf16_t*)((char*)d_ws + (size_t)TOKENS * DIM * 2);

    prep_kernel<<<CAST_BLOCKS + 2048, 256, 0, stream>>>(x, xb, W, A, B, Wt);
    gemm_kernel<<<MB_BLKS * NB_BLKS, 512, 0, stream>>>(xb, Wt, b, out);
}